// Round 4
// baseline (128.650 us; speedup 1.0000x reference)
//
#include <hip/hip_runtime.h>
#include <math.h>

#ifndef __has_builtin
#define __has_builtin(x) 0
#endif

#define GRIDC  32          // cells per axis (256 px / 8 px)
#define NCELL  1024
#define CSHIFT 3           // 8 px cells
#define RAD    4           // +-4 cells => all nodes within 32 px guaranteed included
                           // dropped nodes: D>=32px, |s|>=0.144 -> r <= 2^-147 ~ 0 (ref flushes too)

// ws int-offset map:
//   [0,1024)    q_cnt      [1024,2048) q_cursor
//   [2048,3072) n_cnt      [3072,4096) n_cursor        (all zeroed by memset)
//   [4096,5121) q_start    [5121,6146) n_start
//   [8192, 8192+4N)        q_sorted  int4 {orig_idx, x, y, 0}
//   [8192+4N, +8P)         nodes_sorted  8 floats {px,py,s,w0,w1,w2,0,0}

__device__ __forceinline__ float fast_exp2(float x) {
#if __has_builtin(__builtin_amdgcn_exp2f)
    return __builtin_amdgcn_exp2f(x);
#else
    return exp2f(x);
#endif
}

__device__ __forceinline__ int cell_of(int x, int y) {
    int cx = x >> CSHIFT; cx = cx < 0 ? 0 : (cx > GRIDC - 1 ? GRIDC - 1 : cx);
    int cy = y >> CSHIFT; cy = cy < 0 ? 0 : (cy > GRIDC - 1 ? GRIDC - 1 : cy);
    return (cy << 5) + cx;
}

// ---------------------------------------------------------------------------
__global__ __launch_bounds__(256) void hist_kernel(const int* __restrict__ X,
        const int* __restrict__ pat, int* __restrict__ wsI, int N, int P) {
    int gid = blockIdx.x * 256 + threadIdx.x;
    if (gid < N) {
        atomicAdd(&wsI[0 + cell_of(X[2 * gid], X[2 * gid + 1])], 1);
    } else if (gid < N + P) {
        int p = gid - N;
        atomicAdd(&wsI[2048 + cell_of(pat[2 * p], pat[2 * p + 1])], 1);
    }
}

// Exclusive scan of 1024 counts; block 0 = queries, block 1 = nodes.
__global__ __launch_bounds__(256) void scan_kernel(int* __restrict__ wsI) {
    const int src = blockIdx.x ? 2048 : 0;
    const int dst = blockIdx.x ? 5121 : 4096;
    __shared__ int lds[256];
    int tid = threadIdx.x;
    int c0 = wsI[src + tid * 4 + 0];
    int c1 = wsI[src + tid * 4 + 1];
    int c2 = wsI[src + tid * 4 + 2];
    int c3 = wsI[src + tid * 4 + 3];
    int sum = c0 + c1 + c2 + c3;
    lds[tid] = sum;
    __syncthreads();
    for (int off = 1; off < 256; off <<= 1) {
        int t = (tid >= off) ? lds[tid - off] : 0;
        __syncthreads();
        lds[tid] += t;
        __syncthreads();
    }
    int excl = lds[tid] - sum;
    wsI[dst + tid * 4 + 0] = excl; excl += c0;
    wsI[dst + tid * 4 + 1] = excl; excl += c1;
    wsI[dst + tid * 4 + 2] = excl; excl += c2;
    wsI[dst + tid * 4 + 3] = excl; excl += c3;
    if (tid == 255) wsI[dst + 1024] = lds[255];
}

// Scatter queries into cell order; scatter+pack node constants into cell order.
__global__ __launch_bounds__(256) void scatter_kernel(const int* __restrict__ X,
        const int* __restrict__ pat, const float* __restrict__ W2,
        const float* __restrict__ sig, int* __restrict__ wsI,
        int4* __restrict__ qs, float* __restrict__ nsf, int N, int P) {
    int gid = blockIdx.x * 256 + threadIdx.x;
    if (gid < N) {
        int x = X[2 * gid], y = X[2 * gid + 1];
        int cell = cell_of(x, y);
        int pos = wsI[4096 + cell] + atomicAdd(&wsI[1024 + cell], 1);
        qs[pos] = make_int4(gid, x, y, 0);
    } else if (gid < N + P) {
        int p = gid - N;
        int x = pat[2 * p], y = pat[2 * p + 1];
        int cell = cell_of(x, y);
        int pos = wsI[5121 + cell] + atomicAdd(&wsI[3072 + cell], 1);
        float* r = nsf + (size_t)pos * 8;
        r[0] = (float)x;
        r[1] = (float)y;
        r[2] = -0.7213475204444817f / sig[p];   // -log2(e)/2 / sigma^2
        r[3] = W2[p];
        r[4] = W2[P + p];
        r[5] = W2[2 * P + p];
        r[6] = 0.0f;
        r[7] = 0.0f;
    }
}

// One wave per cell; lanes = queries of that cell. Node lists for a row of
// cells are contiguous (sorted by cell index), and all loop bounds derive from
// blockIdx -> node data arrives wave-uniform via the scalar pipe.
__global__ __launch_bounds__(64) void rbf_cells(const int* __restrict__ wsI,
        const int4* __restrict__ qs, const float4* __restrict__ ns,
        float* __restrict__ out) {
    const int cell = blockIdx.x;
    const int cx = cell & (GRIDC - 1);
    const int cy = cell >> 5;
    const int* __restrict__ qstart = wsI + 4096;
    const int* __restrict__ nstart = wsI + 5121;
    const int q0 = qstart[cell], q1 = qstart[cell + 1];
    const int x0 = cx > RAD ? cx - RAD : 0;
    const int x1 = cx + RAD < GRIDC - 1 ? cx + RAD : GRIDC - 1;
    const int y0 = cy > RAD ? cy - RAD : 0;
    const int y1 = cy + RAD < GRIDC - 1 ? cy + RAD : GRIDC - 1;

    for (int i = q0 + (int)threadIdx.x; i < q1; i += 64) {
        int4 q = qs[i];
        float xf = (float)q.y, yf = (float)q.z;
        float den = 0.f, a0 = 0.f, a1 = 0.f, a2 = 0.f;
        for (int yc = y0; yc <= y1; ++yc) {
            int row = yc << 5;
            int k0 = nstart[row + x0];
            int k1 = nstart[row + x1 + 1];
            for (int k = k0; k < k1; ++k) {
                float4 a = ns[2 * k];
                float4 b = ns[2 * k + 1];
                float dx = xf - a.x;
                float dy = yf - a.y;
                float r = fast_exp2(fmaf(dy, dy, dx * dx) * a.z);
                den += r;
                a0 = fmaf(r, a.w, a0);
                a1 = fmaf(r, b.x, a1);
                a2 = fmaf(r, b.y, a2);
            }
        }
        int n = q.x;
        out[3 * n + 0] = a0 / den;
        out[3 * n + 1] = a1 / den;
        out[3 * n + 2] = a2 / den;
    }
}

// ---------------------------------------------------------------------------
// Generic fallback (unexpected sizes): brute-force N x P sweep.
// ---------------------------------------------------------------------------
__global__ void pack_nodes(const int* __restrict__ pat, const float* __restrict__ W2,
                           const float* __restrict__ sigmaSq, float* __restrict__ nodes,
                           int P) {
    int p = blockIdx.x * blockDim.x + threadIdx.x;
    if (p >= P) return;
    float* q = nodes + 8 * (size_t)p;
    q[0] = (float)pat[2 * p];
    q[1] = (float)pat[2 * p + 1];
    q[2] = -0.7213475204444817f / sigmaSq[p];
    q[3] = W2[p];
    q[4] = W2[P + p];
    q[5] = W2[2 * P + p];
    q[6] = 0.0f;
    q[7] = 0.0f;
}

__global__ __launch_bounds__(256) void rbf_main_dyn(const int* __restrict__ X,
                                                    const float* __restrict__ nodes,
                                                    float* __restrict__ outp,
                                                    int N, int P) {
    int n = blockIdx.x * 256 + threadIdx.x;
    if (n >= N) return;
    float xn = (float)X[2 * n], yn = (float)X[2 * n + 1];
    float den = 0.f, a0 = 0.f, a1 = 0.f, a2 = 0.f;
    for (int j = 0; j < P; ++j) {
        const float* q = nodes + (size_t)j * 8;
        float dx = xn - q[0], dy = yn - q[1];
        float r = fast_exp2(fmaf(dy, dy, dx * dx) * q[2]);
        den += r;
        a0 = fmaf(r, q[3], a0);
        a1 = fmaf(r, q[4], a1);
        a2 = fmaf(r, q[5], a2);
    }
    outp[3 * n + 0] = a0 / den;
    outp[3 * n + 1] = a1 / den;
    outp[3 * n + 2] = a2 / den;
}

extern "C" void kernel_launch(void* const* d_in, const int* in_sizes, int n_in,
                              void* d_out, int out_size, void* d_ws, size_t ws_size,
                              hipStream_t stream) {
    const int*   X   = (const int*)d_in[0];
    const int*   pat = (const int*)d_in[1];
    const float* W2  = (const float*)d_in[2];
    const float* sig = (const float*)d_in[3];
    float*       out = (float*)d_out;

    const int N = in_sizes[0] / 2;
    const int P = in_sizes[3];

    int* wsI = (int*)d_ws;
    size_t need = ((size_t)8192 + 4 * (size_t)N + 8 * (size_t)P) * sizeof(int);

    if (ws_size >= need && out_size == 3 * N && (N & 3) == 0) {
        int4*  qs  = (int4*)(wsI + 8192);
        float* nsf = (float*)(wsI + 8192 + 4 * (size_t)N);
        int total = N + P;

        hipMemsetAsync(d_ws, 0, 4096 * sizeof(int), stream);   // counters + cursors
        hist_kernel<<<dim3((total + 255) / 256), dim3(256), 0, stream>>>(X, pat, wsI, N, P);
        scan_kernel<<<dim3(2), dim3(256), 0, stream>>>(wsI);
        scatter_kernel<<<dim3((total + 255) / 256), dim3(256), 0, stream>>>(
            X, pat, W2, sig, wsI, qs, nsf, N, P);
        rbf_cells<<<dim3(NCELL), dim3(64), 0, stream>>>(wsI, qs, (const float4*)nsf, out);
    } else {
        float* nodes = (float*)d_ws;
        pack_nodes<<<dim3((P + 255) / 256), dim3(256), 0, stream>>>(pat, W2, sig, nodes, P);
        rbf_main_dyn<<<dim3((N + 255) / 256), dim3(256), 0, stream>>>(X, nodes, out, N, P);
    }
}

// Round 5
// 118.891 us; speedup vs baseline: 1.0821x; 1.0821x over previous
//
#include <hip/hip_runtime.h>
#include <math.h>

#ifndef __has_builtin
#define __has_builtin(x) 0
#endif

#define GRIDC  32          // cells per axis (256 px / 8 px)
#define NCELL  1024
#define CSHIFT 3           // 8 px cells
#define RAD    4           // +-4 cells => all nodes within 32 px included
                           // dropped nodes: D>=32px, |s|>=0.144 -> r <= 2^-147 ~ 0 (ref flushes too)

// ws int-offset map:
//   [0,1024)    q_cnt      [1024,2048) q_cursor
//   [2048,3072) n_cnt      [3072,4096) n_cursor        (all zeroed by memset)
//   [4096,5121) q_start    [5121,6146) n_start
//   [8192, 8192+4N)        q_sorted  int4 {orig_idx, x, y, 0}
//   [8192+4N, +8P)         nodes_sorted  8 floats {px,py,s,w0,w1,w2,0,0}

__device__ __forceinline__ float fast_exp2(float x) {
#if __has_builtin(__builtin_amdgcn_exp2f)
    return __builtin_amdgcn_exp2f(x);
#else
    return exp2f(x);
#endif
}

__device__ __forceinline__ int cell_of(int x, int y) {
    int cx = x >> CSHIFT; cx = cx < 0 ? 0 : (cx > GRIDC - 1 ? GRIDC - 1 : cx);
    int cy = y >> CSHIFT; cy = cy < 0 ? 0 : (cy > GRIDC - 1 ? GRIDC - 1 : cy);
    return (cy << 5) + cx;
}

// ---------------------------------------------------------------------------
__global__ __launch_bounds__(256) void hist_kernel(const int* __restrict__ X,
        const int* __restrict__ pat, int* __restrict__ wsI, int N, int P) {
    int gid = blockIdx.x * 256 + threadIdx.x;
    if (gid < N) {
        atomicAdd(&wsI[0 + cell_of(X[2 * gid], X[2 * gid + 1])], 1);
    } else if (gid < N + P) {
        int p = gid - N;
        atomicAdd(&wsI[2048 + cell_of(pat[2 * p], pat[2 * p + 1])], 1);
    }
}

// Exclusive scan of 1024 counts; block 0 = queries, block 1 = nodes.
__global__ __launch_bounds__(256) void scan_kernel(int* __restrict__ wsI) {
    const int src = blockIdx.x ? 2048 : 0;
    const int dst = blockIdx.x ? 5121 : 4096;
    __shared__ int lds[256];
    int tid = threadIdx.x;
    int c0 = wsI[src + tid * 4 + 0];
    int c1 = wsI[src + tid * 4 + 1];
    int c2 = wsI[src + tid * 4 + 2];
    int c3 = wsI[src + tid * 4 + 3];
    int sum = c0 + c1 + c2 + c3;
    lds[tid] = sum;
    __syncthreads();
    for (int off = 1; off < 256; off <<= 1) {
        int t = (tid >= off) ? lds[tid - off] : 0;
        __syncthreads();
        lds[tid] += t;
        __syncthreads();
    }
    int excl = lds[tid] - sum;
    wsI[dst + tid * 4 + 0] = excl; excl += c0;
    wsI[dst + tid * 4 + 1] = excl; excl += c1;
    wsI[dst + tid * 4 + 2] = excl; excl += c2;
    wsI[dst + tid * 4 + 3] = excl; excl += c3;
    if (tid == 255) wsI[dst + 1024] = lds[255];
}

// Scatter queries into cell order; scatter+pack node constants into cell order.
__global__ __launch_bounds__(256) void scatter_kernel(const int* __restrict__ X,
        const int* __restrict__ pat, const float* __restrict__ W2,
        const float* __restrict__ sig, int* __restrict__ wsI,
        int4* __restrict__ qs, float* __restrict__ nsf, int N, int P) {
    int gid = blockIdx.x * 256 + threadIdx.x;
    if (gid < N) {
        int x = X[2 * gid], y = X[2 * gid + 1];
        int cell = cell_of(x, y);
        int pos = wsI[4096 + cell] + atomicAdd(&wsI[1024 + cell], 1);
        qs[pos] = make_int4(gid, x, y, 0);
    } else if (gid < N + P) {
        int p = gid - N;
        int x = pat[2 * p], y = pat[2 * p + 1];
        int cell = cell_of(x, y);
        int pos = wsI[5121 + cell] + atomicAdd(&wsI[3072 + cell], 1);
        float* r = nsf + (size_t)pos * 8;
        r[0] = (float)x;
        r[1] = (float)y;
        r[2] = -0.7213475204444817f / sig[p];   // -log2(e)/2 / sigma^2
        r[3] = W2[p];
        r[4] = W2[P + p];
        r[5] = W2[2 * P + p];
        r[6] = 0.0f;
        r[7] = 0.0f;
    }
}

// ---------------------------------------------------------------------------
// Per-cell RBF, 9 waves per block: wave w handles neighborhood row y0+w
// (~18 node-iters), partials to LDS, wave 0 reduces + divides + writes.
// Node-list bounds derive from blockIdx + wave id -> wave-uniform -> scalar
// pipe (s_load) for all node data. 1024 blocks x 576 thr = 27 waves/CU.
// ---------------------------------------------------------------------------
__global__ __launch_bounds__(576) void rbf_cells9(const int* __restrict__ wsI,
        const int4* __restrict__ qs, const float4* __restrict__ ns,
        float* __restrict__ out) {
    __shared__ float4 acc[9][64];   // 9 KB
    const int cell = blockIdx.x;
    const int cx = cell & (GRIDC - 1);
    const int cy = cell >> 5;
    const int wave = threadIdx.x >> 6;   // 0..8
    const int lane = threadIdx.x & 63;
    const int* __restrict__ qstart = wsI + 4096;
    const int* __restrict__ nstart = wsI + 5121;
    const int q0 = qstart[cell], q1 = qstart[cell + 1];
    const int x0 = cx - RAD < 0 ? 0 : cx - RAD;
    const int x1 = cx + RAD > GRIDC - 1 ? GRIDC - 1 : cx + RAD;
    const int y0 = cy - RAD < 0 ? 0 : cy - RAD;
    const int y1 = cy + RAD > GRIDC - 1 ? GRIDC - 1 : cy + RAD;

    const int yc = y0 + wave;
    int k0 = 0, k1 = 0;
    if (yc <= y1) {
        int row = yc << 5;
        k0 = nstart[row + x0];
        k1 = nstart[row + x1 + 1];
    }

    for (int base = q0; base < q1; base += 64) {
        const int i = base + lane;
        float den = 0.f, a0 = 0.f, a1 = 0.f, a2 = 0.f;
        if (i < q1) {
            int4 q = qs[i];
            float xf = (float)q.y, yf = (float)q.z;
            for (int k = k0; k < k1; ++k) {
                float4 a = ns[2 * k];
                float4 b = ns[2 * k + 1];
                float dx = xf - a.x;
                float dy = yf - a.y;
                float r = fast_exp2(fmaf(dy, dy, dx * dx) * a.z);
                den += r;
                a0 = fmaf(r, a.w, a0);
                a1 = fmaf(r, b.x, a1);
                a2 = fmaf(r, b.y, a2);
            }
        }
        acc[wave][lane] = make_float4(den, a0, a1, a2);
        __syncthreads();
        if (threadIdx.x < 64 && i < q1) {
            float4 t = acc[0][lane];
#pragma unroll
            for (int w = 1; w < 9; ++w) {
                float4 u = acc[w][lane];
                t.x += u.x; t.y += u.y; t.z += u.z; t.w += u.w;
            }
            int n = qs[i].x;
            float inv = 1.0f / t.x;
            out[3 * n + 0] = t.y * inv;
            out[3 * n + 1] = t.z * inv;
            out[3 * n + 2] = t.w * inv;
        }
        __syncthreads();
    }
}

// ---------------------------------------------------------------------------
// Generic fallback (unexpected sizes): brute-force N x P sweep.
// ---------------------------------------------------------------------------
__global__ void pack_nodes(const int* __restrict__ pat, const float* __restrict__ W2,
                           const float* __restrict__ sigmaSq, float* __restrict__ nodes,
                           int P) {
    int p = blockIdx.x * blockDim.x + threadIdx.x;
    if (p >= P) return;
    float* q = nodes + 8 * (size_t)p;
    q[0] = (float)pat[2 * p];
    q[1] = (float)pat[2 * p + 1];
    q[2] = -0.7213475204444817f / sigmaSq[p];
    q[3] = W2[p];
    q[4] = W2[P + p];
    q[5] = W2[2 * P + p];
    q[6] = 0.0f;
    q[7] = 0.0f;
}

__global__ __launch_bounds__(256) void rbf_main_dyn(const int* __restrict__ X,
                                                    const float* __restrict__ nodes,
                                                    float* __restrict__ outp,
                                                    int N, int P) {
    int n = blockIdx.x * 256 + threadIdx.x;
    if (n >= N) return;
    float xn = (float)X[2 * n], yn = (float)X[2 * n + 1];
    float den = 0.f, a0 = 0.f, a1 = 0.f, a2 = 0.f;
    for (int j = 0; j < P; ++j) {
        const float* q = nodes + (size_t)j * 8;
        float dx = xn - q[0], dy = yn - q[1];
        float r = fast_exp2(fmaf(dy, dy, dx * dx) * q[2]);
        den += r;
        a0 = fmaf(r, q[3], a0);
        a1 = fmaf(r, q[4], a1);
        a2 = fmaf(r, q[5], a2);
    }
    outp[3 * n + 0] = a0 / den;
    outp[3 * n + 1] = a1 / den;
    outp[3 * n + 2] = a2 / den;
}

extern "C" void kernel_launch(void* const* d_in, const int* in_sizes, int n_in,
                              void* d_out, int out_size, void* d_ws, size_t ws_size,
                              hipStream_t stream) {
    const int*   X   = (const int*)d_in[0];
    const int*   pat = (const int*)d_in[1];
    const float* W2  = (const float*)d_in[2];
    const float* sig = (const float*)d_in[3];
    float*       out = (float*)d_out;

    const int N = in_sizes[0] / 2;
    const int P = in_sizes[3];

    int* wsI = (int*)d_ws;
    size_t need = ((size_t)8192 + 4 * (size_t)N + 8 * (size_t)P) * sizeof(int);

    if (ws_size >= need && out_size == 3 * N && (N & 3) == 0) {
        int4*  qs  = (int4*)(wsI + 8192);
        float* nsf = (float*)(wsI + 8192 + 4 * (size_t)N);
        int total = N + P;

        hipMemsetAsync(d_ws, 0, 4096 * sizeof(int), stream);   // counters + cursors
        hist_kernel<<<dim3((total + 255) / 256), dim3(256), 0, stream>>>(X, pat, wsI, N, P);
        scan_kernel<<<dim3(2), dim3(256), 0, stream>>>(wsI);
        scatter_kernel<<<dim3((total + 255) / 256), dim3(256), 0, stream>>>(
            X, pat, W2, sig, wsI, qs, nsf, N, P);
        rbf_cells9<<<dim3(NCELL), dim3(576), 0, stream>>>(wsI, qs, (const float4*)nsf, out);
    } else {
        float* nodes = (float*)d_ws;
        pack_nodes<<<dim3((P + 255) / 256), dim3(256), 0, stream>>>(pat, W2, sig, nodes, P);
        rbf_main_dyn<<<dim3((N + 255) / 256), dim3(256), 0, stream>>>(X, nodes, out, N, P);
    }
}

// Round 6
// 105.374 us; speedup vs baseline: 1.2209x; 1.1283x over previous
//
#include <hip/hip_runtime.h>
#include <math.h>

#ifndef __has_builtin
#define __has_builtin(x) 0
#endif

#define GRIDC  32          // cells per axis (256 px / 8 px)
#define NCELL  1024
#define CSHIFT 3           // 8 px cells
#define RAD    4           // +-4 cells => all nodes within 32 px included
#define WIN    9           // 2*RAD+1
#define NCAP   12          // node slots per cell (Poisson mean 2; overflow -> global list, exact)
#define QCAP   128         // query slots per cell (Poisson mean 64; overflow -> brute list, exact)

// ws int-offset map:
#define OFF_QOVF_CNT 0
#define OFF_NOVF_CNT 1
#define OFF_QCNT     64                        // 1024 ints
#define OFF_NCNT     1088                      // 1024 ints
#define OFF_QB       4096                      // NCELL*QCAP int4  = 524288 ints (2 MB)
#define OFF_NB       (4096 + 524288)           // NCELL*NCAP*8 floats = 98304 ints
#define OFF_NOVF     (OFF_NB + 98304)          // up to 2048 nodes * 8 floats = 16384 ints
#define OFF_QOVF     (OFF_NOVF + 16384)        // up to N int4

__device__ __forceinline__ float fast_exp2(float x) {
#if __has_builtin(__builtin_amdgcn_exp2f)
    return __builtin_amdgcn_exp2f(x);
#else
    return exp2f(x);
#endif
}

__device__ __forceinline__ int cell_of(int x, int y) {
    int cx = x >> CSHIFT; cx = cx < 0 ? 0 : (cx > GRIDC - 1 ? GRIDC - 1 : cx);
    int cy = y >> CSHIFT; cy = cy < 0 ? 0 : (cy > GRIDC - 1 ? GRIDC - 1 : cy);
    return (cy << 5) + cx;
}

// ---------------------------------------------------------------------------
// Scatter into fixed-capacity buckets (no hist/scan needed). Overflow goes to
// exact-correct global lists.
// ---------------------------------------------------------------------------
__global__ __launch_bounds__(256) void scatter_bucket(const int* __restrict__ X,
        const int* __restrict__ pat, const float* __restrict__ W2,
        const float* __restrict__ sig, int* __restrict__ wsI, int N, int P) {
    int gid = blockIdx.x * 256 + threadIdx.x;
    if (gid < N) {
        int x = X[2 * gid], y = X[2 * gid + 1];
        int cell = cell_of(x, y);
        int slot = atomicAdd(&wsI[OFF_QCNT + cell], 1);
        int4 rec = make_int4(gid, x, y, 0);
        if (slot < QCAP) {
            ((int4*)(wsI + OFF_QB))[cell * QCAP + slot] = rec;
        } else {
            int o = atomicAdd(&wsI[OFF_QOVF_CNT], 1);
            ((int4*)(wsI + OFF_QOVF))[o] = rec;
        }
    } else if (gid < N + P) {
        int p = gid - N;
        int x = pat[2 * p], y = pat[2 * p + 1];
        int cell = cell_of(x, y);
        int slot = atomicAdd(&wsI[OFF_NCNT + cell], 1);
        float* dst;
        if (slot < NCAP) {
            dst = (float*)(wsI + OFF_NB) + (size_t)(cell * NCAP + slot) * 8;
        } else {
            int o = atomicAdd(&wsI[OFF_NOVF_CNT], 1);
            dst = (float*)(wsI + OFF_NOVF) + (size_t)o * 8;
        }
        dst[0] = (float)x;
        dst[1] = (float)y;
        dst[2] = -0.7213475204444817f / sig[p];   // -log2(e)/2 / sigma^2
        dst[3] = W2[p];
        dst[4] = W2[P + p];
        dst[5] = W2[2 * P + p];
        dst[6] = 0.0f;
        dst[7] = 0.0f;
    }
}

// ---------------------------------------------------------------------------
// Per-cell RBF with LDS-staged node neighborhood (one coalesced burst, then
// broadcast LDS reads — removes the one-load-in-flight ~400cyc/iter chain).
// 9 waves/block: wave w handles window row w; wave 8 also adds overflow nodes.
// ---------------------------------------------------------------------------
__global__ __launch_bounds__(576) void rbf_cells_lds(const int* __restrict__ wsI,
                                                     float* __restrict__ out) {
    __shared__ float4 sn[WIN * WIN * NCAP * 2];   // 1944 float4 = 31.1 KB
    __shared__ int    scnt[WIN * WIN];            // 81
    __shared__ float4 acc[9][64];                 // 9 KB

    const int cell = blockIdx.x;
    const int cx = cell & (GRIDC - 1);
    const int cy = cell >> 5;
    const int tid = threadIdx.x;
    const int wave = tid >> 6;
    const int lane = tid & 63;

    const int*    qcnt = wsI + OFF_QCNT;
    const int*    ncnt = wsI + OFF_NCNT;
    const int4*   qb   = (const int4*)(wsI + OFF_QB);
    const float4* nb   = (const float4*)(wsI + OFF_NB);
    const float4* novf = (const float4*)(wsI + OFF_NOVF);
    const int novfc = wsI[OFF_NOVF_CNT];

    // ---- stage per-window-cell counts ----
    if (tid < WIN * WIN) {
        int wy = tid / WIN, wx = tid - wy * WIN;
        int gy = cy - RAD + wy, gx = cx - RAD + wx;
        int v = 0;
        if ((unsigned)gy < GRIDC && (unsigned)gx < GRIDC) {
            int c = (gy << 5) + gx;
            v = ncnt[c];
            v = v > NCAP ? NCAP : v;
        }
        scnt[tid] = v;
    }
    // ---- stage node data (all slots; garbage beyond cnt never read) ----
    for (int idx = tid; idx < WIN * WIN * NCAP * 2; idx += 576) {
        int wcell = idx / (NCAP * 2);
        int rem   = idx - wcell * (NCAP * 2);
        int wy = wcell / WIN, wx = wcell - wy * WIN;
        int gy = cy - RAD + wy, gx = cx - RAD + wx;
        if ((unsigned)gy < GRIDC && (unsigned)gx < GRIDC) {
            int c = (gy << 5) + gx;
            sn[idx] = nb[c * (NCAP * 2) + rem];
        }
    }
    __syncthreads();

    // ---- per-cell queries, chunks of 64 ----
    int qn = qcnt[cell];
    qn = qn > QCAP ? QCAP : qn;

    for (int base = 0; base < qn; base += 64) {
        const int i = base + lane;
        float den = 0.f, a0 = 0.f, a1 = 0.f, a2 = 0.f;
        if (i < qn) {
            int4 q = qb[cell * QCAP + i];
            float xf = (float)q.y, yf = (float)q.z;
            const int cbase = wave * WIN;
#pragma unroll
            for (int wx = 0; wx < WIN; ++wx) {
                int c = cbase + wx;
                int nc = scnt[c];
                int lb = c * (NCAP * 2);
                for (int s = 0; s < nc; ++s) {
                    float4 a = sn[lb + 2 * s];
                    float4 b = sn[lb + 2 * s + 1];
                    float dx = xf - a.x;
                    float dy = yf - a.y;
                    float r = fast_exp2(fmaf(dy, dy, dx * dx) * a.z);
                    den += r;
                    a0 = fmaf(r, a.w, a0);
                    a1 = fmaf(r, b.x, a1);
                    a2 = fmaf(r, b.y, a2);
                }
            }
            if (wave == 8) {             // overflow nodes: added for ALL queries (exact)
                for (int j = 0; j < novfc; ++j) {
                    float4 a = novf[2 * j];
                    float4 b = novf[2 * j + 1];
                    float dx = xf - a.x;
                    float dy = yf - a.y;
                    float r = fast_exp2(fmaf(dy, dy, dx * dx) * a.z);
                    den += r;
                    a0 = fmaf(r, a.w, a0);
                    a1 = fmaf(r, b.x, a1);
                    a2 = fmaf(r, b.y, a2);
                }
            }
        }
        acc[wave][lane] = make_float4(den, a0, a1, a2);
        __syncthreads();
        if (tid < 64 && i < qn) {
            float4 t = acc[0][lane];
#pragma unroll
            for (int w = 1; w < 9; ++w) {
                float4 u = acc[w][lane];
                t.x += u.x; t.y += u.y; t.z += u.z; t.w += u.w;
            }
            int n = qb[cell * QCAP + i].x;
            float inv = 1.0f / t.x;
            out[3 * n + 0] = t.y * inv;
            out[3 * n + 1] = t.z * inv;
            out[3 * n + 2] = t.w * inv;
        }
        __syncthreads();
    }

    // ---- overflow queries (usually zero): grid-stride brute force ----
    int qovc = wsI[OFF_QOVF_CNT];
    for (int oi = blockIdx.x * 576 + tid; oi < qovc; oi += NCELL * 576) {
        int4 q = ((const int4*)(wsI + OFF_QOVF))[oi];
        float xf = (float)q.y, yf = (float)q.z;
        int qcx = q.y >> CSHIFT, qcy = q.z >> CSHIFT;
        int x0 = qcx - RAD < 0 ? 0 : qcx - RAD;
        int x1 = qcx + RAD > GRIDC - 1 ? GRIDC - 1 : qcx + RAD;
        int y0 = qcy - RAD < 0 ? 0 : qcy - RAD;
        int y1 = qcy + RAD > GRIDC - 1 ? GRIDC - 1 : qcy + RAD;
        float den = 0.f, a0 = 0.f, a1 = 0.f, a2 = 0.f;
        for (int gy = y0; gy <= y1; ++gy) {
            for (int gx = x0; gx <= x1; ++gx) {
                int c = (gy << 5) + gx;
                int nc = ncnt[c]; nc = nc > NCAP ? NCAP : nc;
                for (int s = 0; s < nc; ++s) {
                    float4 a = nb[(c * NCAP + s) * 2];
                    float4 b = nb[(c * NCAP + s) * 2 + 1];
                    float dx = xf - a.x;
                    float dy = yf - a.y;
                    float r = fast_exp2(fmaf(dy, dy, dx * dx) * a.z);
                    den += r;
                    a0 = fmaf(r, a.w, a0);
                    a1 = fmaf(r, b.x, a1);
                    a2 = fmaf(r, b.y, a2);
                }
            }
        }
        for (int j = 0; j < novfc; ++j) {
            float4 a = novf[2 * j];
            float4 b = novf[2 * j + 1];
            float dx = xf - a.x;
            float dy = yf - a.y;
            float r = fast_exp2(fmaf(dy, dy, dx * dx) * a.z);
            den += r;
            a0 = fmaf(r, a.w, a0);
            a1 = fmaf(r, b.x, a1);
            a2 = fmaf(r, b.y, a2);
        }
        int n = q.x;
        float inv = 1.0f / den;
        out[3 * n + 0] = a0 * inv;
        out[3 * n + 1] = a1 * inv;
        out[3 * n + 2] = a2 * inv;
    }
}

// ---------------------------------------------------------------------------
// Generic fallback (unexpected sizes): brute-force N x P sweep.
// ---------------------------------------------------------------------------
__global__ void pack_nodes(const int* __restrict__ pat, const float* __restrict__ W2,
                           const float* __restrict__ sigmaSq, float* __restrict__ nodes,
                           int P) {
    int p = blockIdx.x * blockDim.x + threadIdx.x;
    if (p >= P) return;
    float* q = nodes + 8 * (size_t)p;
    q[0] = (float)pat[2 * p];
    q[1] = (float)pat[2 * p + 1];
    q[2] = -0.7213475204444817f / sigmaSq[p];
    q[3] = W2[p];
    q[4] = W2[P + p];
    q[5] = W2[2 * P + p];
    q[6] = 0.0f;
    q[7] = 0.0f;
}

__global__ __launch_bounds__(256) void rbf_main_dyn(const int* __restrict__ X,
                                                    const float* __restrict__ nodes,
                                                    float* __restrict__ outp,
                                                    int N, int P) {
    int n = blockIdx.x * 256 + threadIdx.x;
    if (n >= N) return;
    float xn = (float)X[2 * n], yn = (float)X[2 * n + 1];
    float den = 0.f, a0 = 0.f, a1 = 0.f, a2 = 0.f;
    for (int j = 0; j < P; ++j) {
        const float* q = nodes + (size_t)j * 8;
        float dx = xn - q[0], dy = yn - q[1];
        float r = fast_exp2(fmaf(dy, dy, dx * dx) * q[2]);
        den += r;
        a0 = fmaf(r, q[3], a0);
        a1 = fmaf(r, q[4], a1);
        a2 = fmaf(r, q[5], a2);
    }
    outp[3 * n + 0] = a0 / den;
    outp[3 * n + 1] = a1 / den;
    outp[3 * n + 2] = a2 / den;
}

extern "C" void kernel_launch(void* const* d_in, const int* in_sizes, int n_in,
                              void* d_out, int out_size, void* d_ws, size_t ws_size,
                              hipStream_t stream) {
    const int*   X   = (const int*)d_in[0];
    const int*   pat = (const int*)d_in[1];
    const float* W2  = (const float*)d_in[2];
    const float* sig = (const float*)d_in[3];
    float*       out = (float*)d_out;

    const int N = in_sizes[0] / 2;
    const int P = in_sizes[3];

    int* wsI = (int*)d_ws;
    size_t need = ((size_t)OFF_QOVF + 4 * (size_t)N) * sizeof(int);

    if (ws_size >= need && out_size == 3 * N && P <= 2048) {
        // zero overflow counters + per-cell cursors
        hipMemsetAsync(d_ws, 0, (OFF_NCNT + NCELL) * sizeof(int), stream);
        int total = N + P;
        scatter_bucket<<<dim3((total + 255) / 256), dim3(256), 0, stream>>>(
            X, pat, W2, sig, wsI, N, P);
        rbf_cells_lds<<<dim3(NCELL), dim3(576), 0, stream>>>(wsI, out);
    } else {
        float* nodes = (float*)d_ws;
        pack_nodes<<<dim3((P + 255) / 256), dim3(256), 0, stream>>>(pat, W2, sig, nodes, P);
        rbf_main_dyn<<<dim3((N + 255) / 256), dim3(256), 0, stream>>>(X, nodes, out, N, P);
    }
}

// Round 7
// 80.931 us; speedup vs baseline: 1.5896x; 1.3020x over previous
//
#include <hip/hip_runtime.h>
#include <math.h>

#ifndef __has_builtin
#define __has_builtin(x) 0
#endif

#define GRIDC  32          // cells per axis (256 px / 8 px)
#define NCELL  1024
#define CSHIFT 3           // 8 px cells
#define RAD    4           // +-4 cells => all nodes within 32 px included
                           // dropped: D>=32px, sigmaSq<=5 -> r <= exp(-102.4) = 2^-147 (flushes, ref too)

// ws int map:
//   [0, 1025)                    starts (exclusive scan of per-cell node counts, +total)
//   [2048, 2048+2048*4)          A: float4 {px, py, s, w0} per node, cell-sorted
//   [10240, 10240+2048*2)        B: float2 {w1, w2} per node, cell-sorted
#define OFF_A 2048
#define OFF_B 10240
#define WS_NEED_INTS (10240 + 4096)

__device__ __forceinline__ float fast_exp2(float x) {
#if __has_builtin(__builtin_amdgcn_exp2f)
    return __builtin_amdgcn_exp2f(x);
#else
    return exp2f(x);
#endif
}

__device__ __forceinline__ int cell_of(int x, int y) {
    int cx = x >> CSHIFT; cx = cx < 0 ? 0 : (cx > GRIDC - 1 ? GRIDC - 1 : cx);
    int cy = y >> CSHIFT; cy = cy < 0 ? 0 : (cy > GRIDC - 1 ? GRIDC - 1 : cy);
    return (cy << 5) + cx;
}

// ---------------------------------------------------------------------------
// ONE block, 1024 threads: histogram node cells in LDS, scan, emit compacted
// cell-sorted node records. No global atomics, no separate memset dispatch.
// Handles P <= 2048 (2 nodes per thread).
// ---------------------------------------------------------------------------
__global__ __launch_bounds__(1024) void bin_nodes(const int* __restrict__ pat,
        const float* __restrict__ W2, const float* __restrict__ sig,
        int* __restrict__ wsI, int P) {
    __shared__ int cnt[NCELL];
    __shared__ int buf[NCELL];
    const int tid = threadIdx.x;
    cnt[tid] = 0;
    __syncthreads();

    int cell0 = -1, slot0 = 0, cell1 = -1, slot1 = 0;
    if (tid < P) {
        cell0 = cell_of(pat[2 * tid], pat[2 * tid + 1]);
        slot0 = atomicAdd(&cnt[cell0], 1);          // LDS atomic
    }
    const int p1 = tid + 1024;
    if (p1 < P) {
        cell1 = cell_of(pat[2 * p1], pat[2 * p1 + 1]);
        slot1 = atomicAdd(&cnt[cell1], 1);
    }
    __syncthreads();

    const int c = cnt[tid];
    buf[tid] = c;
    __syncthreads();
    for (int off = 1; off < NCELL; off <<= 1) {
        int t = (tid >= off) ? buf[tid - off] : 0;
        __syncthreads();
        buf[tid] += t;
        __syncthreads();
    }
    const int excl = buf[tid] - c;
    wsI[tid] = excl;
    if (tid == NCELL - 1) wsI[NCELL] = buf[tid];
    cnt[tid] = excl;                                 // reuse as start[]
    __syncthreads();

    float4* __restrict__ A = (float4*)(wsI + OFF_A);
    float2* __restrict__ B = (float2*)(wsI + OFF_B);
    if (cell0 >= 0) {
        int pos = cnt[cell0] + slot0;
        A[pos] = make_float4((float)pat[2 * tid], (float)pat[2 * tid + 1],
                             -0.7213475204444817f / sig[tid], W2[tid]);
        B[pos] = make_float2(W2[P + tid], W2[2 * P + tid]);
    }
    if (cell1 >= 0) {
        int pos = cnt[cell1] + slot1;
        A[pos] = make_float4((float)pat[2 * p1], (float)pat[2 * p1 + 1],
                             -0.7213475204444817f / sig[p1], W2[p1]);
        B[pos] = make_float2(W2[P + p1], W2[2 * P + p1]);
    }
}

// ---------------------------------------------------------------------------
// 512 blocks x 256 thr: stage ALL node records + starts into LDS (coalesced),
// then 2 threads per query (window rows 0-4 / 5-8) walk per-cell node lists
// with divergent LDS reads. Queries stay in original order -> coalesced X
// loads and out stores. 55.3 KB LDS -> 2 blocks/CU, 8 waves/CU all active.
// ---------------------------------------------------------------------------
__global__ __launch_bounds__(256) void rbf_win(const int* __restrict__ X,
        const int* __restrict__ wsI, float* __restrict__ out, int N, int P) {
    __shared__ float4 sA[2048];       // 32 KB
    __shared__ float2 sB[2048];       // 16 KB
    __shared__ int    sst[NCELL + 1]; // 4.1 KB
    __shared__ float4 accb[128];      // 2 KB

    const int tid = threadIdx.x;
    const float4* __restrict__ A = (const float4*)(wsI + OFF_A);
    const float2* __restrict__ B = (const float2*)(wsI + OFF_B);
    for (int i = tid; i < P; i += 256) { sA[i] = A[i]; sB[i] = B[i]; }
    for (int i = tid; i < NCELL + 1; i += 256) sst[i] = wsI[i];
    __syncthreads();

    const int half = tid >> 7;            // 0: rows 0-4, 1: rows 5-8
    const int qi   = tid & 127;
    const int n    = blockIdx.x * 128 + qi;
    const bool act = n < N;

    float xf = 0.f, yf = 0.f;
    int cx = 0, cy = 0;
    if (act) {
        int2 xy = ((const int2*)X)[n];
        xf = (float)xy.x; yf = (float)xy.y;
        cx = xy.x >> CSHIFT; cx = cx < 0 ? 0 : (cx > GRIDC - 1 ? GRIDC - 1 : cx);
        cy = xy.y >> CSHIFT; cy = cy < 0 ? 0 : (cy > GRIDC - 1 ? GRIDC - 1 : cy);
    }

    float den = 0.f, a0 = 0.f, a1 = 0.f, a2 = 0.f;
    if (act) {
        const int x0 = cx - RAD < 0 ? 0 : cx - RAD;
        const int x1 = cx + RAD > GRIDC - 1 ? GRIDC - 1 : cx + RAD;
        const int r0 = half ? 5 : 0;
        const int r1 = half ? 9 : 5;
        for (int r = r0; r < r1; ++r) {
            int gy = cy - RAD + r;
            if ((unsigned)gy >= GRIDC) continue;
            int row = gy << 5;
            int k0 = sst[row + x0];
            int k1 = sst[row + x1 + 1];
            for (int k = k0; k < k1; ++k) {
                float4 a = sA[k];
                float2 b = sB[k];
                float dx = xf - a.x;
                float dy = yf - a.y;
                float rr = fast_exp2(fmaf(dy, dy, dx * dx) * a.z);
                den += rr;
                a0 = fmaf(rr, a.w, a0);
                a1 = fmaf(rr, b.x, a1);
                a2 = fmaf(rr, b.y, a2);
            }
        }
    }

    if (half) accb[qi] = make_float4(den, a0, a1, a2);
    __syncthreads();
    if (!half && act) {
        float4 u = accb[qi];
        den += u.x; a0 += u.y; a1 += u.z; a2 += u.w;
        float inv = 1.0f / den;
        out[3 * n + 0] = a0 * inv;
        out[3 * n + 1] = a1 * inv;
        out[3 * n + 2] = a2 * inv;
    }
}

// ---------------------------------------------------------------------------
// Generic fallback (unexpected sizes): brute-force N x P sweep.
// ---------------------------------------------------------------------------
__global__ void pack_nodes(const int* __restrict__ pat, const float* __restrict__ W2,
                           const float* __restrict__ sigmaSq, float* __restrict__ nodes,
                           int P) {
    int p = blockIdx.x * blockDim.x + threadIdx.x;
    if (p >= P) return;
    float* q = nodes + 8 * (size_t)p;
    q[0] = (float)pat[2 * p];
    q[1] = (float)pat[2 * p + 1];
    q[2] = -0.7213475204444817f / sigmaSq[p];
    q[3] = W2[p];
    q[4] = W2[P + p];
    q[5] = W2[2 * P + p];
    q[6] = 0.0f;
    q[7] = 0.0f;
}

__global__ __launch_bounds__(256) void rbf_main_dyn(const int* __restrict__ X,
                                                    const float* __restrict__ nodes,
                                                    float* __restrict__ outp,
                                                    int N, int P) {
    int n = blockIdx.x * 256 + threadIdx.x;
    if (n >= N) return;
    float xn = (float)X[2 * n], yn = (float)X[2 * n + 1];
    float den = 0.f, a0 = 0.f, a1 = 0.f, a2 = 0.f;
    for (int j = 0; j < P; ++j) {
        const float* q = nodes + (size_t)j * 8;
        float dx = xn - q[0], dy = yn - q[1];
        float r = fast_exp2(fmaf(dy, dy, dx * dx) * q[2]);
        den += r;
        a0 = fmaf(r, q[3], a0);
        a1 = fmaf(r, q[4], a1);
        a2 = fmaf(r, q[5], a2);
    }
    outp[3 * n + 0] = a0 / den;
    outp[3 * n + 1] = a1 / den;
    outp[3 * n + 2] = a2 / den;
}

extern "C" void kernel_launch(void* const* d_in, const int* in_sizes, int n_in,
                              void* d_out, int out_size, void* d_ws, size_t ws_size,
                              hipStream_t stream) {
    const int*   X   = (const int*)d_in[0];
    const int*   pat = (const int*)d_in[1];
    const float* W2  = (const float*)d_in[2];
    const float* sig = (const float*)d_in[3];
    float*       out = (float*)d_out;

    const int N = in_sizes[0] / 2;
    const int P = in_sizes[3];

    int* wsI = (int*)d_ws;

    if (P <= 2048 && out_size == 3 * N && ws_size >= WS_NEED_INTS * sizeof(int)) {
        bin_nodes<<<dim3(1), dim3(1024), 0, stream>>>(pat, W2, sig, wsI, P);
        rbf_win<<<dim3((N + 127) / 128), dim3(256), 0, stream>>>(X, wsI, out, N, P);
    } else {
        float* nodes = (float*)d_ws;
        pack_nodes<<<dim3((P + 255) / 256), dim3(256), 0, stream>>>(pat, W2, sig, nodes, P);
        rbf_main_dyn<<<dim3((N + 255) / 256), dim3(256), 0, stream>>>(X, nodes, out, N, P);
    }
}

// Round 8
// 76.340 us; speedup vs baseline: 1.6852x; 1.0601x over previous
//
#include <hip/hip_runtime.h>
#include <math.h>

#ifndef __has_builtin
#define __has_builtin(x) 0
#endif

#define GRIDC  32          // cells per axis (256 px / 8 px)
#define NCELL  1024
#define CSHIFT 3           // 8 px cells
#define RAD    4           // +-4 cells => all nodes within 32 px included
                           // dropped: D>=32px, sigmaSq<=5 -> r <= exp(-102.4) = 2^-147 (flushes, ref too)

__device__ __forceinline__ float fast_exp2(float x) {
#if __has_builtin(__builtin_amdgcn_exp2f)
    return __builtin_amdgcn_exp2f(x);
#else
    return exp2f(x);
#endif
}

__device__ __forceinline__ int cell_of(int x, int y) {
    int cx = x >> CSHIFT; cx = cx < 0 ? 0 : (cx > GRIDC - 1 ? GRIDC - 1 : cx);
    int cy = y >> CSHIFT; cy = cy < 0 ? 0 : (cy > GRIDC - 1 ? GRIDC - 1 : cy);
    return (cy << 5) + cx;
}

// ---------------------------------------------------------------------------
// Single fused kernel. Each block (256 thr, 128 queries):
//   Phase 1: bin ALL nodes into LDS itself (inputs are 48 KB, L2/L3-hot):
//            LDS histogram -> 256-thread scan of 1024 cells -> scatter into
//            cell-sorted sA/sB in LDS. ~2 us, fully parallel across blocks;
//            removes the separate bin dispatch + global A/B round-trip.
//   Phase 2: 2 threads per query (window rows 0-4 / 5-8) walk per-cell node
//            lists with LDS reads; halves combined via LDS; coalesced X loads
//            and out stores (queries in original order).
// LDS: 32K sA + 16K sB + 4.1K sst + 1K part + 2K accb = 55.2 KB -> 2 blocks/CU.
// ---------------------------------------------------------------------------
__global__ __launch_bounds__(256) void rbf_fused(const int* __restrict__ X,
        const int* __restrict__ pat, const float* __restrict__ W2,
        const float* __restrict__ sig, float* __restrict__ out, int N, int P) {
    __shared__ float4 sA[2048];        // {px, py, s, w0}
    __shared__ float2 sB[2048];        // {w1, w2}
    __shared__ int    sst[NCELL + 1];  // counts -> exclusive starts
    __shared__ int    part[256];       // scan partials
    __shared__ float4 accb[128];       // half-1 partials

    const int tid = threadIdx.x;

    // ---- Phase 1a: zero counts ----
    for (int i = tid; i < NCELL + 1; i += 256) sst[i] = 0;
    __syncthreads();

    // ---- Phase 1b: histogram (up to 8 nodes/thread, coalesced) ----
    int cellr[8], slotr[8], xr[8], yr[8];
#pragma unroll
    for (int j = 0; j < 8; ++j) {
        int p = j * 256 + tid;
        cellr[j] = -1;
        if (p < P) {
            int2 xy = ((const int2*)pat)[p];
            xr[j] = xy.x; yr[j] = xy.y;
            int c = cell_of(xy.x, xy.y);
            cellr[j] = c;
            slotr[j] = atomicAdd(&sst[c], 1);
        }
    }
    __syncthreads();

    // ---- Phase 1c: exclusive scan of 1024 counts (thread t owns 4) ----
    const int c0 = sst[4 * tid], c1 = sst[4 * tid + 1];
    const int c2 = sst[4 * tid + 2], c3 = sst[4 * tid + 3];
    const int sum = c0 + c1 + c2 + c3;
    part[tid] = sum;
    __syncthreads();
    for (int off = 1; off < 256; off <<= 1) {
        int t = (tid >= off) ? part[tid - off] : 0;
        __syncthreads();
        part[tid] += t;
        __syncthreads();
    }
    int excl = part[tid] - sum;
    sst[4 * tid + 0] = excl; excl += c0;
    sst[4 * tid + 1] = excl; excl += c1;
    sst[4 * tid + 2] = excl; excl += c2;
    sst[4 * tid + 3] = excl;
    if (tid == 255) sst[NCELL] = part[255];
    __syncthreads();

    // ---- Phase 1d: scatter node records into cell-sorted LDS ----
#pragma unroll
    for (int j = 0; j < 8; ++j) {
        if (cellr[j] >= 0) {
            int p = j * 256 + tid;
            int pos = sst[cellr[j]] + slotr[j];
            sA[pos] = make_float4((float)xr[j], (float)yr[j],
                                  -0.7213475204444817f / sig[p], W2[p]);
            sB[pos] = make_float2(W2[P + p], W2[2 * P + p]);
        }
    }
    __syncthreads();

    // ---- Phase 2: RBF, 2 threads per query ----
    const int half = tid >> 7;            // 0: window rows 0-4, 1: rows 5-8
    const int qi   = tid & 127;
    const int n    = blockIdx.x * 128 + qi;
    const bool act = n < N;

    float xf = 0.f, yf = 0.f;
    int cx = 0, cy = 0;
    if (act) {
        int2 xy = ((const int2*)X)[n];
        xf = (float)xy.x; yf = (float)xy.y;
        cx = xy.x >> CSHIFT; cx = cx < 0 ? 0 : (cx > GRIDC - 1 ? GRIDC - 1 : cx);
        cy = xy.y >> CSHIFT; cy = cy < 0 ? 0 : (cy > GRIDC - 1 ? GRIDC - 1 : cy);
    }

    float den = 0.f, a0 = 0.f, a1 = 0.f, a2 = 0.f;
    if (act) {
        const int x0 = cx - RAD < 0 ? 0 : cx - RAD;
        const int x1 = cx + RAD > GRIDC - 1 ? GRIDC - 1 : cx + RAD;
        const int r0 = half ? 5 : 0;
        const int r1 = half ? 9 : 5;
        for (int r = r0; r < r1; ++r) {
            int gy = cy - RAD + r;
            if ((unsigned)gy >= GRIDC) continue;
            int row = gy << 5;
            int k0 = sst[row + x0];
            int k1 = sst[row + x1 + 1];
            for (int k = k0; k < k1; ++k) {
                float4 a = sA[k];
                float2 b = sB[k];
                float dx = xf - a.x;
                float dy = yf - a.y;
                float rr = fast_exp2(fmaf(dy, dy, dx * dx) * a.z);
                den += rr;
                a0 = fmaf(rr, a.w, a0);
                a1 = fmaf(rr, b.x, a1);
                a2 = fmaf(rr, b.y, a2);
            }
        }
    }

    if (half) accb[qi] = make_float4(den, a0, a1, a2);
    __syncthreads();
    if (!half && act) {
        float4 u = accb[qi];
        den += u.x; a0 += u.y; a1 += u.z; a2 += u.w;
        float inv = 1.0f / den;
        out[3 * n + 0] = a0 * inv;
        out[3 * n + 1] = a1 * inv;
        out[3 * n + 2] = a2 * inv;
    }
}

// ---------------------------------------------------------------------------
// Generic fallback (unexpected sizes): brute-force N x P sweep.
// ---------------------------------------------------------------------------
__global__ void pack_nodes(const int* __restrict__ pat, const float* __restrict__ W2,
                           const float* __restrict__ sigmaSq, float* __restrict__ nodes,
                           int P) {
    int p = blockIdx.x * blockDim.x + threadIdx.x;
    if (p >= P) return;
    float* q = nodes + 8 * (size_t)p;
    q[0] = (float)pat[2 * p];
    q[1] = (float)pat[2 * p + 1];
    q[2] = -0.7213475204444817f / sigmaSq[p];
    q[3] = W2[p];
    q[4] = W2[P + p];
    q[5] = W2[2 * P + p];
    q[6] = 0.0f;
    q[7] = 0.0f;
}

__global__ __launch_bounds__(256) void rbf_main_dyn(const int* __restrict__ X,
                                                    const float* __restrict__ nodes,
                                                    float* __restrict__ outp,
                                                    int N, int P) {
    int n = blockIdx.x * 256 + threadIdx.x;
    if (n >= N) return;
    float xn = (float)X[2 * n], yn = (float)X[2 * n + 1];
    float den = 0.f, a0 = 0.f, a1 = 0.f, a2 = 0.f;
    for (int j = 0; j < P; ++j) {
        const float* q = nodes + (size_t)j * 8;
        float dx = xn - q[0], dy = yn - q[1];
        float r = fast_exp2(fmaf(dy, dy, dx * dx) * q[2]);
        den += r;
        a0 = fmaf(r, q[3], a0);
        a1 = fmaf(r, q[4], a1);
        a2 = fmaf(r, q[5], a2);
    }
    outp[3 * n + 0] = a0 / den;
    outp[3 * n + 1] = a1 / den;
    outp[3 * n + 2] = a2 / den;
}

extern "C" void kernel_launch(void* const* d_in, const int* in_sizes, int n_in,
                              void* d_out, int out_size, void* d_ws, size_t ws_size,
                              hipStream_t stream) {
    const int*   X   = (const int*)d_in[0];
    const int*   pat = (const int*)d_in[1];
    const float* W2  = (const float*)d_in[2];
    const float* sig = (const float*)d_in[3];
    float*       out = (float*)d_out;

    const int N = in_sizes[0] / 2;
    const int P = in_sizes[3];

    if (P <= 2048 && out_size == 3 * N) {
        rbf_fused<<<dim3((N + 127) / 128), dim3(256), 0, stream>>>(
            X, pat, W2, sig, out, N, P);
    } else {
        float* nodes = (float*)d_ws;
        pack_nodes<<<dim3((P + 255) / 256), dim3(256), 0, stream>>>(pat, W2, sig, nodes, P);
        rbf_main_dyn<<<dim3((N + 255) / 256), dim3(256), 0, stream>>>(X, nodes, out, N, P);
    }
}

// Round 9
// 73.045 us; speedup vs baseline: 1.7612x; 1.0451x over previous
//
#include <hip/hip_runtime.h>
#include <math.h>

#ifndef __has_builtin
#define __has_builtin(x) 0
#endif

#define GRIDC  32          // cells per axis (256 px / 8 px)
#define NCELL  1024
#define CSHIFT 3           // 8 px cells
#define RAD    4           // +-4 cells => all nodes within 32 px included.
                           // RAD must stay 4: with RAD=3, a worst-case query
                           // (nearest node ~13px, sigma^2=1) has kept r ~ e^-85
                           // while dropped-at-24px r ~ e^-58 -> output corrupted.
                           // At RAD=4 dropped r <= e^-102 << any kept term.

__device__ __forceinline__ float fast_exp2(float x) {
#if __has_builtin(__builtin_amdgcn_exp2f)
    return __builtin_amdgcn_exp2f(x);
#else
    return exp2f(x);
#endif
}

__device__ __forceinline__ int cell_of(int x, int y) {
    int cx = x >> CSHIFT; cx = cx < 0 ? 0 : (cx > GRIDC - 1 ? GRIDC - 1 : cx);
    int cy = y >> CSHIFT; cy = cy < 0 ? 0 : (cy > GRIDC - 1 ? GRIDC - 1 : cy);
    return (cy << 5) + cx;
}

// ---------------------------------------------------------------------------
// Single fused kernel. Each block: 512 threads, 128 queries (4 threads/query).
//   Phase 1: bin ALL nodes (<=2048) into LDS: histogram (LDS atomics) ->
//            shfl wave-scan + cross-wave scan (2 barriers total, vs 18 for
//            Hillis-Steele) -> scatter cell-sorted {px,py,s,w0}/{w1,w2}.
//   Phase 2: thread quarter q walks window rows [9q/4, 9(q+1)/4) (2-3 rows,
//            ~40 node-iters) with LDS reads; quarters reduced via LDS.
// LDS ~59.5 KB -> 2 blocks/CU; grid 512 = 2 blocks/CU, 16 waves/CU.
// ---------------------------------------------------------------------------
__global__ __launch_bounds__(512) void rbf_fused(const int* __restrict__ X,
        const int* __restrict__ pat, const float* __restrict__ W2,
        const float* __restrict__ sig, float* __restrict__ out, int N, int P) {
    __shared__ float4 sA[2048];        // {px, py, s, w0}   32 KB
    __shared__ float2 sB[2048];        // {w1, w2}          16 KB
    __shared__ int    sst[NCELL + 1];  // counts -> starts   4.1 KB
    __shared__ float4 accb[3 * 128];   // quarter partials   6 KB
    __shared__ int    wsum[8];

    const int tid  = threadIdx.x;
    const int lane = tid & 63;
    const int wv   = tid >> 6;

    // ---- Phase 1a: zero counts ----
    for (int i = tid; i < NCELL + 1; i += 512) sst[i] = 0;
    __syncthreads();

    // ---- Phase 1b: histogram (up to 4 nodes/thread, coalesced) ----
    int cellr[4], slotr[4], xr[4], yr[4];
#pragma unroll
    for (int j = 0; j < 4; ++j) {
        int p = j * 512 + tid;
        cellr[j] = -1;
        if (p < P) {
            int2 xy = ((const int2*)pat)[p];
            xr[j] = xy.x; yr[j] = xy.y;
            int c = cell_of(xy.x, xy.y);
            cellr[j] = c;
            slotr[j] = atomicAdd(&sst[c], 1);
        }
    }
    __syncthreads();

    // ---- Phase 1c: exclusive scan of 1024 counts (thread owns 2 cells) ----
    const int c0 = sst[2 * tid], c1 = sst[2 * tid + 1];
    int sum = c0 + c1;
    int incl = sum;
#pragma unroll
    for (int off = 1; off < 64; off <<= 1) {
        int t = __shfl_up(incl, off);
        if (lane >= off) incl += t;
    }
    if (lane == 63) wsum[wv] = incl;
    __syncthreads();
    int base = 0;
#pragma unroll
    for (int w = 0; w < 8; ++w) base += (w < wv) ? wsum[w] : 0;
    const int excl0 = base + incl - sum;        // exclusive start of cell 2*tid
    __syncthreads();                            // all reads of wsum done
    sst[2 * tid + 0] = excl0;
    sst[2 * tid + 1] = excl0 + c0;
    if (tid == 511) sst[NCELL] = excl0 + c0 + c1;
    __syncthreads();

    // ---- Phase 1d: scatter node records into cell-sorted LDS ----
#pragma unroll
    for (int j = 0; j < 4; ++j) {
        if (cellr[j] >= 0) {
            int p = j * 512 + tid;
            int pos = sst[cellr[j]] + slotr[j];
            sA[pos] = make_float4((float)xr[j], (float)yr[j],
                                  -0.7213475204444817f / sig[p], W2[p]);
            sB[pos] = make_float2(W2[P + p], W2[2 * P + p]);
        }
    }
    __syncthreads();

    // ---- Phase 2: RBF, 4 threads per query (window rows split 2/2/2/3) ----
    const int quarter = tid >> 7;          // 0..3
    const int qi      = tid & 127;
    const int n       = blockIdx.x * 128 + qi;
    const bool act    = n < N;

    float den = 0.f, a0 = 0.f, a1 = 0.f, a2 = 0.f;
    if (act) {
        int2 xy = ((const int2*)X)[n];
        const float xf = (float)xy.x, yf = (float)xy.y;
        int cx = xy.x >> CSHIFT; cx = cx < 0 ? 0 : (cx > GRIDC - 1 ? GRIDC - 1 : cx);
        int cy = xy.y >> CSHIFT; cy = cy < 0 ? 0 : (cy > GRIDC - 1 ? GRIDC - 1 : cy);
        const int x0 = cx - RAD < 0 ? 0 : cx - RAD;
        const int x1 = cx + RAD > GRIDC - 1 ? GRIDC - 1 : cx + RAD;
        const int r0 = (9 * quarter) >> 2;         // 0,2,4,6
        const int r1 = (9 * (quarter + 1)) >> 2;   // 2,4,6,9
        for (int r = r0; r < r1; ++r) {
            int gy = cy - RAD + r;
            if ((unsigned)gy >= GRIDC) continue;
            int row = gy << 5;
            int k0 = sst[row + x0];
            int k1 = sst[row + x1 + 1];
            for (int k = k0; k < k1; ++k) {
                float4 a = sA[k];
                float2 b = sB[k];
                float dx = xf - a.x;
                float dy = yf - a.y;
                float rr = fast_exp2(fmaf(dy, dy, dx * dx) * a.z);
                den += rr;
                a0 = fmaf(rr, a.w, a0);
                a1 = fmaf(rr, b.x, a1);
                a2 = fmaf(rr, b.y, a2);
            }
        }
    }

    if (quarter) accb[(quarter - 1) * 128 + qi] = make_float4(den, a0, a1, a2);
    __syncthreads();
    if (quarter == 0 && act) {
#pragma unroll
        for (int w = 0; w < 3; ++w) {
            float4 u = accb[w * 128 + qi];
            den += u.x; a0 += u.y; a1 += u.z; a2 += u.w;
        }
        float inv = 1.0f / den;
        out[3 * n + 0] = a0 * inv;
        out[3 * n + 1] = a1 * inv;
        out[3 * n + 2] = a2 * inv;
    }
}

// ---------------------------------------------------------------------------
// Generic fallback (unexpected sizes): brute-force N x P sweep.
// ---------------------------------------------------------------------------
__global__ void pack_nodes(const int* __restrict__ pat, const float* __restrict__ W2,
                           const float* __restrict__ sigmaSq, float* __restrict__ nodes,
                           int P) {
    int p = blockIdx.x * blockDim.x + threadIdx.x;
    if (p >= P) return;
    float* q = nodes + 8 * (size_t)p;
    q[0] = (float)pat[2 * p];
    q[1] = (float)pat[2 * p + 1];
    q[2] = -0.7213475204444817f / sigmaSq[p];
    q[3] = W2[p];
    q[4] = W2[P + p];
    q[5] = W2[2 * P + p];
    q[6] = 0.0f;
    q[7] = 0.0f;
}

__global__ __launch_bounds__(256) void rbf_main_dyn(const int* __restrict__ X,
                                                    const float* __restrict__ nodes,
                                                    float* __restrict__ outp,
                                                    int N, int P) {
    int n = blockIdx.x * 256 + threadIdx.x;
    if (n >= N) return;
    float xn = (float)X[2 * n], yn = (float)X[2 * n + 1];
    float den = 0.f, a0 = 0.f, a1 = 0.f, a2 = 0.f;
    for (int j = 0; j < P; ++j) {
        const float* q = nodes + (size_t)j * 8;
        float dx = xn - q[0], dy = yn - q[1];
        float r = fast_exp2(fmaf(dy, dy, dx * dx) * q[2]);
        den += r;
        a0 = fmaf(r, q[3], a0);
        a1 = fmaf(r, q[4], a1);
        a2 = fmaf(r, q[5], a2);
    }
    outp[3 * n + 0] = a0 / den;
    outp[3 * n + 1] = a1 / den;
    outp[3 * n + 2] = a2 / den;
}

extern "C" void kernel_launch(void* const* d_in, const int* in_sizes, int n_in,
                              void* d_out, int out_size, void* d_ws, size_t ws_size,
                              hipStream_t stream) {
    const int*   X   = (const int*)d_in[0];
    const int*   pat = (const int*)d_in[1];
    const float* W2  = (const float*)d_in[2];
    const float* sig = (const float*)d_in[3];
    float*       out = (float*)d_out;

    const int N = in_sizes[0] / 2;
    const int P = in_sizes[3];

    if (P <= 2048 && out_size == 3 * N) {
        rbf_fused<<<dim3((N + 127) / 128), dim3(512), 0, stream>>>(
            X, pat, W2, sig, out, N, P);
    } else {
        float* nodes = (float*)d_ws;
        pack_nodes<<<dim3((P + 255) / 256), dim3(256), 0, stream>>>(pat, W2, sig, nodes, P);
        rbf_main_dyn<<<dim3((N + 255) / 256), dim3(256), 0, stream>>>(X, nodes, out, N, P);
    }
}

// Round 10
// 72.119 us; speedup vs baseline: 1.7839x; 1.0128x over previous
//
#include <hip/hip_runtime.h>
#include <math.h>

#ifndef __has_builtin
#define __has_builtin(x) 0
#endif

#define GRIDC  32          // cells per axis (256 px / 8 px)
#define NCELL  1024
#define CSHIFT 3           // 8 px cells
#define RAD    4           // +-4 cells => all nodes within 32 px included.
                           // RAD must stay 4: with RAD=3 a worst-case query
                           // (nearest node ~13px, sigma^2=1) keeps r ~ e^-85
                           // while dropping r ~ e^-58 -> output corrupted.
                           // At RAD=4 dropped r <= e^-102 << any kept term.

__device__ __forceinline__ float fast_exp2(float x) {
#if __has_builtin(__builtin_amdgcn_exp2f)
    return __builtin_amdgcn_exp2f(x);
#else
    return exp2f(x);
#endif
}

__device__ __forceinline__ int cell_of(int x, int y) {
    int cx = x >> CSHIFT; cx = cx < 0 ? 0 : (cx > GRIDC - 1 ? GRIDC - 1 : cx);
    int cy = y >> CSHIFT; cy = cy < 0 ? 0 : (cy > GRIDC - 1 ? GRIDC - 1 : cy);
    return (cy << 5) + cx;
}

// ---------------------------------------------------------------------------
// Single fused kernel. Each block: 512 threads, 128 queries (4 threads/query).
//   Phase 1: bin ALL nodes (<=2048) into LDS: histogram (LDS atomics) ->
//            shfl wave-scan (2 barriers) -> scatter cell-sorted records.
//   Phase 2: thread quarter walks window rows [9q/4, 9(q+1)/4) with the inner
//            node loop SOFTWARE-PIPELINED: node k+1's record is prefetched
//            into registers while node k is computed, so the LDS waitcnt
//            overlaps the ~34-cyc compute instead of serializing with it.
// LDS ~59.5 KB -> 2 blocks/CU; grid 512 = 2 blocks/CU, 16 waves/CU.
// ---------------------------------------------------------------------------
__global__ __launch_bounds__(512) void rbf_fused(const int* __restrict__ X,
        const int* __restrict__ pat, const float* __restrict__ W2,
        const float* __restrict__ sig, float* __restrict__ out, int N, int P) {
    __shared__ float4 sA[2048];        // {px, py, s, w0}   32 KB
    __shared__ float2 sB[2048];        // {w1, w2}          16 KB
    __shared__ int    sst[NCELL + 1];  // counts -> starts   4.1 KB
    __shared__ float4 accb[3 * 128];   // quarter partials   6 KB
    __shared__ int    wsum[8];

    const int tid  = threadIdx.x;
    const int lane = tid & 63;
    const int wv   = tid >> 6;

    // ---- Phase 1a: zero counts ----
    for (int i = tid; i < NCELL + 1; i += 512) sst[i] = 0;
    __syncthreads();

    // ---- Phase 1b: histogram (up to 4 nodes/thread, coalesced) ----
    int cellr[4], slotr[4], xr[4], yr[4];
#pragma unroll
    for (int j = 0; j < 4; ++j) {
        int p = j * 512 + tid;
        cellr[j] = -1;
        if (p < P) {
            int2 xy = ((const int2*)pat)[p];
            xr[j] = xy.x; yr[j] = xy.y;
            int c = cell_of(xy.x, xy.y);
            cellr[j] = c;
            slotr[j] = atomicAdd(&sst[c], 1);
        }
    }
    __syncthreads();

    // ---- Phase 1c: exclusive scan of 1024 counts (thread owns 2 cells) ----
    const int c0 = sst[2 * tid], c1 = sst[2 * tid + 1];
    int sum = c0 + c1;
    int incl = sum;
#pragma unroll
    for (int off = 1; off < 64; off <<= 1) {
        int t = __shfl_up(incl, off);
        if (lane >= off) incl += t;
    }
    if (lane == 63) wsum[wv] = incl;
    __syncthreads();
    int base = 0;
#pragma unroll
    for (int w = 0; w < 8; ++w) base += (w < wv) ? wsum[w] : 0;
    const int excl0 = base + incl - sum;        // exclusive start of cell 2*tid
    __syncthreads();                            // all reads of wsum done
    sst[2 * tid + 0] = excl0;
    sst[2 * tid + 1] = excl0 + c0;
    if (tid == 511) sst[NCELL] = excl0 + c0 + c1;
    __syncthreads();

    // ---- Phase 1d: scatter node records into cell-sorted LDS ----
#pragma unroll
    for (int j = 0; j < 4; ++j) {
        if (cellr[j] >= 0) {
            int p = j * 512 + tid;
            int pos = sst[cellr[j]] + slotr[j];
            sA[pos] = make_float4((float)xr[j], (float)yr[j],
                                  -0.7213475204444817f / sig[p], W2[p]);
            sB[pos] = make_float2(W2[P + p], W2[2 * P + p]);
        }
    }
    __syncthreads();

    // ---- Phase 2: RBF, 4 threads per query (window rows split 2/2/2/3) ----
    const int quarter = tid >> 7;          // 0..3
    const int qi      = tid & 127;
    const int n       = blockIdx.x * 128 + qi;
    const bool act    = n < N;

    float den = 0.f, acc0 = 0.f, acc1 = 0.f, acc2 = 0.f;
    if (act) {
        int2 xy = ((const int2*)X)[n];
        const float xf = (float)xy.x, yf = (float)xy.y;
        int cx = xy.x >> CSHIFT; cx = cx < 0 ? 0 : (cx > GRIDC - 1 ? GRIDC - 1 : cx);
        int cy = xy.y >> CSHIFT; cy = cy < 0 ? 0 : (cy > GRIDC - 1 ? GRIDC - 1 : cy);
        const int x0 = cx - RAD < 0 ? 0 : cx - RAD;
        const int x1 = cx + RAD > GRIDC - 1 ? GRIDC - 1 : cx + RAD;
        const int r0 = (9 * quarter) >> 2;         // 0,2,4,6
        const int r1 = (9 * (quarter + 1)) >> 2;   // 2,4,6,9
        for (int r = r0; r < r1; ++r) {
            int gy = cy - RAD + r;
            if ((unsigned)gy >= GRIDC) continue;
            int row = gy << 5;
            int k0 = sst[row + x0];
            int k1 = sst[row + x1 + 1];
            if (k0 >= k1) continue;
            // software pipeline: registers hold node k; prefetch k+1 (clamped)
            float4 a = sA[k0];
            float2 b = sB[k0];
            for (int k = k0; k < k1; ++k) {
                int kn = k + 1 < k1 ? k + 1 : k;
                float4 an = sA[kn];
                float2 bn = sB[kn];
                float dx = xf - a.x;
                float dy = yf - a.y;
                float rr = fast_exp2(fmaf(dy, dy, dx * dx) * a.z);
                den  += rr;
                acc0 = fmaf(rr, a.w, acc0);
                acc1 = fmaf(rr, b.x, acc1);
                acc2 = fmaf(rr, b.y, acc2);
                a = an; b = bn;
            }
        }
    }

    if (quarter) accb[(quarter - 1) * 128 + qi] = make_float4(den, acc0, acc1, acc2);
    __syncthreads();
    if (quarter == 0 && act) {
#pragma unroll
        for (int w = 0; w < 3; ++w) {
            float4 u = accb[w * 128 + qi];
            den += u.x; acc0 += u.y; acc1 += u.z; acc2 += u.w;
        }
        float inv = 1.0f / den;
        out[3 * n + 0] = acc0 * inv;
        out[3 * n + 1] = acc1 * inv;
        out[3 * n + 2] = acc2 * inv;
    }
}

// ---------------------------------------------------------------------------
// Generic fallback (unexpected sizes): brute-force N x P sweep.
// ---------------------------------------------------------------------------
__global__ void pack_nodes(const int* __restrict__ pat, const float* __restrict__ W2,
                           const float* __restrict__ sigmaSq, float* __restrict__ nodes,
                           int P) {
    int p = blockIdx.x * blockDim.x + threadIdx.x;
    if (p >= P) return;
    float* q = nodes + 8 * (size_t)p;
    q[0] = (float)pat[2 * p];
    q[1] = (float)pat[2 * p + 1];
    q[2] = -0.7213475204444817f / sigmaSq[p];
    q[3] = W2[p];
    q[4] = W2[P + p];
    q[5] = W2[2 * P + p];
    q[6] = 0.0f;
    q[7] = 0.0f;
}

__global__ __launch_bounds__(256) void rbf_main_dyn(const int* __restrict__ X,
                                                    const float* __restrict__ nodes,
                                                    float* __restrict__ outp,
                                                    int N, int P) {
    int n = blockIdx.x * 256 + threadIdx.x;
    if (n >= N) return;
    float xn = (float)X[2 * n], yn = (float)X[2 * n + 1];
    float den = 0.f, a0 = 0.f, a1 = 0.f, a2 = 0.f;
    for (int j = 0; j < P; ++j) {
        const float* q = nodes + (size_t)j * 8;
        float dx = xn - q[0], dy = yn - q[1];
        float r = fast_exp2(fmaf(dy, dy, dx * dx) * q[2]);
        den += r;
        a0 = fmaf(r, q[3], a0);
        a1 = fmaf(r, q[4], a1);
        a2 = fmaf(r, q[5], a2);
    }
    outp[3 * n + 0] = a0 / den;
    outp[3 * n + 1] = a1 / den;
    outp[3 * n + 2] = a2 / den;
}

extern "C" void kernel_launch(void* const* d_in, const int* in_sizes, int n_in,
                              void* d_out, int out_size, void* d_ws, size_t ws_size,
                              hipStream_t stream) {
    const int*   X   = (const int*)d_in[0];
    const int*   pat = (const int*)d_in[1];
    const float* W2  = (const float*)d_in[2];
    const float* sig = (const float*)d_in[3];
    float*       out = (float*)d_out;

    const int N = in_sizes[0] / 2;
    const int P = in_sizes[3];

    if (P <= 2048 && out_size == 3 * N) {
        rbf_fused<<<dim3((N + 127) / 128), dim3(512), 0, stream>>>(
            X, pat, W2, sig, out, N, P);
    } else {
        float* nodes = (float*)d_ws;
        pack_nodes<<<dim3((P + 255) / 256), dim3(256), 0, stream>>>(pat, W2, sig, nodes, P);
        rbf_main_dyn<<<dim3((N + 255) / 256), dim3(256), 0, stream>>>(X, nodes, out, N, P);
    }
}